// Round 5
// baseline (69.428 us; speedup 1.0000x reference)
//
#include <hip/hip_runtime.h>

#define NN 4096

// attr = K*(desired_speed*e_goal - vel)*mass, K=2, mass=60, speed=1.5 (all)
//      = 180*e_goal - 120*vel
__device__ inline float4 propagate_one(float2 pos, float2 vel, float2 goal, float2 F) {
    float tgx = goal.x - pos.x, tgy = goal.y - pos.y;
    float dist = sqrtf(tgx * tgx + tgy * tgy);
    float inv = 1.f / (dist + 1e-8f);
    float Fx = F.x + 180.f * (tgx * inv) - 120.f * vel.x;
    float Fy = F.y + 180.f * (tgy * inv) - 120.f * vel.y;
    float vnx = vel.x + Fx * (0.4f / 60.f);
    float vny = vel.y + Fy * (0.4f / 60.f);
    float sp = sqrtf(vnx * vnx + vny * vny);
    float sc = fminf(1.f, 1.5f / (sp + 1e-8f));
    vnx *= sc; vny *= sc;
    return make_float4(pos.x + vnx * 0.4f, pos.y + vny * 0.4f, vnx, vny);
}

// Single fused dispatch. Grid 512 x 1024 threads (16 waves) -> 2 blocks/CU,
// 32 waves/CU (100% occupancy; LDS 32KB/block -> 64KB/CU of 160).
// Block owns 8 agents; 2 waves per agent, each covering half the j-range
// (32 iters/lane), combined via LDS. Every block also redundantly computes
// the robot's (i=0) total force (each wave takes 256 j's) so pos_new[0] and
// the cost epilogue stay block-local. Diagonal pair contributes exactly 0.
// exp folding: 10*exp((0.6-d)/0.71) = exp2(C0E - C1E*d),
//   C1E = log2e/0.71, C0E = (0.6/0.71 + ln10)*log2e
__global__ __launch_bounds__(1024) void fused_step(
    const float* __restrict__ state, const float* __restrict__ cost_in,
    const float* __restrict__ stacked_in, const float* __restrict__ goals,
    const float* __restrict__ robot_init,
    float* __restrict__ out_state, float* __restrict__ out_cost,
    float* __restrict__ out_stacked)
{
    __shared__ float2 sp[NN];      // all positions, 32 KB
    __shared__ float2 sFh[16];     // per-wave half-force for the 8 agents
    __shared__ float2 sR[16];      // per-wave partial of robot force
    __shared__ float2 sPN[8];      // pos_new for the block's 8 agents
    __shared__ float2 sRobot;      // robot pos_new

    const int tid = threadIdx.x;

    // Stage all positions (coalesced float4 loads, 4 per thread).
#pragma unroll
    for (int k = 0; k < 4; ++k) {
        int idx = tid + k * 1024;
        float4 s = reinterpret_cast<const float4*>(state)[idx];
        sp[idx] = make_float2(s.x, s.y);
    }
    __syncthreads();

    const int wave = tid >> 6, lane = tid & 63;
    const int agent = wave >> 1;              // 0..7 within block
    const int half  = wave & 1;               // which j-half
    const int i = blockIdx.x * 8 + agent;
    const float2 pi = sp[i];                  // lane-uniform broadcast
    const float2 p0 = sp[0];

    const float C1E = 2.0319648462f;
    const float C0E = 4.5411071f;

    float fx = 0.f, fy = 0.f, rfx = 0.f, rfy = 0.f;
    const int jb = half * 2048;
#pragma unroll 8
    for (int t = 0; t < 32; ++t) {
        float2 q = sp[jb + t * 64 + lane];
        float dx = pi.x - q.x, dy = pi.y - q.y;
        float d2 = fmaf(dy, dy, fmaf(dx, dx, 1e-8f));
        float inv_d = __builtin_amdgcn_rsqf(d2);
        float e = __builtin_amdgcn_exp2f(fmaf(-C1E, d2 * inv_d, C0E));
        float w = e * inv_d;
        fx = fmaf(w, dx, fx); fy = fmaf(w, dy, fy);
    }
#pragma unroll
    for (int t = 0; t < 4; ++t) {   // this wave's slice of the robot's force
        float2 q = sp[wave * 256 + t * 64 + lane];
        float dx = p0.x - q.x, dy = p0.y - q.y;
        float d2 = fmaf(dy, dy, fmaf(dx, dx, 1e-8f));
        float inv_d = __builtin_amdgcn_rsqf(d2);
        float e = __builtin_amdgcn_exp2f(fmaf(-C1E, d2 * inv_d, C0E));
        float w = e * inv_d;
        rfx = fmaf(w, dx, rfx); rfy = fmaf(w, dy, rfy);
    }
#pragma unroll
    for (int off = 32; off > 0; off >>= 1) {   // 64-lane butterfly
        fx  += __shfl_xor(fx,  off);
        fy  += __shfl_xor(fy,  off);
        rfx += __shfl_xor(rfx, off);
        rfy += __shfl_xor(rfy, off);
    }
    if (lane == 0) { sFh[wave] = make_float2(fx, fy); sR[wave] = make_float2(rfx, rfy); }
    __syncthreads();

    if (tid < 8) {                  // propagate the block's 8 agents
        int iw = blockIdx.x * 8 + tid;
        float2 F = make_float2(sFh[2 * tid].x + sFh[2 * tid + 1].x,
                               sFh[2 * tid].y + sFh[2 * tid + 1].y);
        float4 s = reinterpret_cast<const float4*>(state)[iw];
        float2 g = reinterpret_cast<const float2*>(goals)[iw];
        float4 r = propagate_one(make_float2(s.x, s.y), make_float2(s.z, s.w), g, F);
        reinterpret_cast<float4*>(out_state)[iw] = r;
        sPN[tid] = make_float2(r.x, r.y);
    } else if (tid == 31) {         // robot pose (redundant per block)
        float2 F0 = make_float2(0.f, 0.f);
#pragma unroll
        for (int c = 0; c < 16; ++c) { F0.x += sR[c].x; F0.y += sR[c].y; }
        float4 s0 = reinterpret_cast<const float4*>(state)[0];
        float2 g0 = reinterpret_cast<const float2*>(goals)[0];
        float4 r = propagate_one(make_float2(s0.x, s0.y), make_float2(s0.z, s0.w), g0, F0);
        sRobot = make_float2(r.x, r.y);
    } else if (tid >= 64 && tid < 72) {      // stacked[N:2N] = state
        int iw = blockIdx.x * 8 + (tid - 64);
        reinterpret_cast<float4*>(out_stacked)[NN + iw] =
            reinterpret_cast<const float4*>(state)[iw];
    } else if (tid >= 128 && tid < 136) {    // stacked[0:N] = stacked_in
        int iw = blockIdx.x * 8 + (tid - 128);
        reinterpret_cast<float4*>(out_stacked)[iw] =
            reinterpret_cast<const float4*>(stacked_in)[iw];
    }
    __syncthreads();

    if (tid < 8) {                  // cost epilogue (needs robot pos_new)
        int iw = blockIdx.x * 8 + tid;
        float2 rp = sRobot;
        float r0x = robot_init[0], r0y = robot_init[1];
        float gdx = goals[0] - r0x, gdy = goals[1] - r0y;
        float PG = (gdx * (rp.x - r0x) + gdy * (rp.y - r0y))
                 / (sqrtf(gdx * gdx + gdy * gdy) + 0.001f);
        float2 pn = sPN[tid];
        float ddx = pn.x - rp.x, ddy = pn.y - rp.y;
        float dist = sqrtf(ddx * ddx + ddy * ddy + 0.001f);
        float blame = (iw == 0) ? 0.f
                    : __builtin_amdgcn_exp2f(dist * -1.2022458675f); // exp(-d/1.2)
        out_cost[iw] = cost_in[iw] + (-4.f * PG + blame);
    }
}

extern "C" void kernel_launch(void* const* d_in, const int* in_sizes, int n_in,
                              void* d_out, int out_size, void* d_ws, size_t ws_size,
                              hipStream_t stream) {
    const float* state      = (const float*)d_in[0];   // (N,4)
    const float* cost       = (const float*)d_in[1];   // (N,1)
    const float* stacked_in = (const float*)d_in[2];   // (N,4)
    const float* goals      = (const float*)d_in[3];   // (N,2)
    const float* robot_init = (const float*)d_in[4];   // (2,)

    float* out         = (float*)d_out;
    float* out_state   = out;               // N*4
    float* out_cost    = out + NN * 4;      // N
    float* out_stacked = out + NN * 5;      // 2N*4

    fused_step<<<NN / 8, 1024, 0, stream>>>(state, cost, stacked_in, goals,
                                            robot_init, out_state, out_cost,
                                            out_stacked);
}